// Round 2
// baseline (553.871 us; speedup 1.0000x reference)
//
#include <hip/hip_runtime.h>

#define L 2048
#define D 2048
#define NH 16
#define HD 128

typedef __attribute__((ext_vector_type(8))) _Float16 half8;
typedef __attribute__((ext_vector_type(4))) float f32x4;

// ---------------- f32 -> fp16 convert ----------------
__global__ void cvt_kernel(const float* __restrict__ in, _Float16* __restrict__ out, int n4) {
    int idx = blockIdx.x * blockDim.x + threadIdx.x;
    int stride = gridDim.x * blockDim.x;
    for (int i = idx; i < n4; i += stride) {
        float4 v = reinterpret_cast<const float4*>(in)[i];
        union { _Float16 h[4]; uint2 u; } pk;
        pk.h[0] = (_Float16)v.x; pk.h[1] = (_Float16)v.y;
        pk.h[2] = (_Float16)v.z; pk.h[3] = (_Float16)v.w;
        reinterpret_cast<uint2*>(out)[i] = pk.u;
    }
}

// ---------------- NT GEMM: C[M][N] = A[M][K] * B[N][K]^T ----------------
// EPI 0: scatter qkv -> qk[t][h][l][d] (t<2) and vt[h][d][l] (t==2), fp16
// EPI 1: write f32 C row-major to Cout
template <int EPI>
__global__ __launch_bounds__(256) void gemm_nt(
    const _Float16* __restrict__ A, const _Float16* __restrict__ B,
    float* __restrict__ Cout, _Float16* __restrict__ qk, _Float16* __restrict__ vt,
    int M, int N, int K)
{
    int wid = threadIdx.x >> 6;
    int lane = threadIdx.x & 63;
    int wr = wid >> 1, wc = wid & 1;
    int m0 = blockIdx.x * 128 + wr * 64;
    int n0 = blockIdx.y * 128 + wc * 64;
    int lr = lane & 15;   // row/col within 16
    int lg = lane >> 4;   // group 0..3

    f32x4 acc[4][4];
#pragma unroll
    for (int i = 0; i < 4; i++)
#pragma unroll
        for (int j = 0; j < 4; j++)
            acc[i][j] = (f32x4){0.f, 0.f, 0.f, 0.f};

    for (int k0 = 0; k0 < K; k0 += 32) {
        int ko = k0 + lg * 8;
        half8 a[4], b[4];
#pragma unroll
        for (int i = 0; i < 4; i++)
            a[i] = *reinterpret_cast<const half8*>(A + (size_t)(m0 + i * 16 + lr) * K + ko);
#pragma unroll
        for (int j = 0; j < 4; j++)
            b[j] = *reinterpret_cast<const half8*>(B + (size_t)(n0 + j * 16 + lr) * K + ko);
#pragma unroll
        for (int i = 0; i < 4; i++)
#pragma unroll
            for (int j = 0; j < 4; j++)
                acc[i][j] = __builtin_amdgcn_mfma_f32_16x16x32_f16(a[i], b[j], acc[i][j], 0, 0, 0);
    }

#pragma unroll
    for (int i = 0; i < 4; i++) {
#pragma unroll
        for (int j = 0; j < 4; j++) {
#pragma unroll
            for (int r = 0; r < 4; r++) {
                int row = m0 + i * 16 + lg * 4 + r;  // C layout: row=(lane>>4)*4+reg
                int col = n0 + j * 16 + lr;          //           col=lane&15
                float v = acc[i][j][r];
                if (EPI == 0) {
                    int t = col >> 11;
                    int w2 = col & 2047;
                    int h = w2 >> 7, d = w2 & 127;
                    if (t < 2) {
                        qk[(((size_t)t * NH + h) * L + row) * HD + d] = (_Float16)v;
                    } else {
                        vt[((size_t)h * HD + d) * L + row] = (_Float16)v;
                    }
                } else {
                    Cout[(size_t)row * N + col] = v;
                }
            }
        }
    }
}

// ---------------- fused RMSNorm + RoPE on q and k planes (in place) ----------------
__global__ void norm_rope(_Float16* __restrict__ qk) {
    int wid = threadIdx.x >> 6, lane = threadIdx.x & 63;
    int row = blockIdx.x * 4 + wid;      // 0 .. 2*NH*L-1
    int l = row & (L - 1);
    int th = row >> 11;                  // t*NH + h, 0..31
    _Float16* p = qk + ((size_t)th * L + l) * HD + lane * 2;
    float x0 = (float)p[0];
    float x1 = (float)p[1];
    float ss = x0 * x0 + x1 * x1;
#pragma unroll
    for (int off = 1; off < 64; off <<= 1) ss += __shfl_xor(ss, off);
    float r = rsqrtf(ss * (1.0f / 128.0f) + 1e-5f);
    float n0 = x0 * r, n1 = x1 * r;
    // RoPE pair index i = lane, angle = l * base^(-2i/128)
    float freq = expf(-(float)(2 * lane) * (1.0f / 128.0f) * logf(100000.0f));
    float ang = (float)l * freq;
    float s, c;
    sincosf(ang, &s, &c);
    // out[2i] = t[2i+1]*cos - t[2i]*sin ; out[2i+1] = t[2i+1]*sin + t[2i]*cos
    p[0] = (_Float16)(n1 * c - n0 * s);
    p[1] = (_Float16)(n1 * s + n0 * c);
}

// ---------------- causal flash attention, v2 ----------------
// No online max (scores bounded: q,k RMS-normed => |s|<=sqrt(128); use static
// offset 4). No shuffles in the main loop. KVBLK=64. Heavy q-tiles first.
// grid (L/64, NH), block 256 (4 waves). Wave w owns q rows qt*64 + w*16.
__global__ __launch_bounds__(256) void attn_kernel(
    const _Float16* __restrict__ qk, const _Float16* __restrict__ vt,
    _Float16* __restrict__ out)
{
    __shared__ __align__(16) _Float16 plds[4][16 * 64];
    int wid = threadIdx.x >> 6, lane = threadIdx.x & 63;
    int h = blockIdx.y;
    int qt = gridDim.x - 1 - blockIdx.x;   // heavy q-tiles launch first
    int q0 = qt * 64 + wid * 16;
    int lr = lane & 15, lg = lane >> 4;

    const _Float16* qn = qk + (size_t)h * L * HD;              // q plane
    const _Float16* kn = qk + ((size_t)(NH + h) * L) * HD;     // k plane
    const _Float16* vp = vt + (size_t)h * HD * L;              // v^T plane

    half8 qa[4];
#pragma unroll
    for (int kk = 0; kk < 4; kk++)
        qa[kk] = *reinterpret_cast<const half8*>(qn + (size_t)(q0 + lr) * HD + kk * 32 + lg * 8);

    f32x4 oacc[8];
#pragma unroll
    for (int jo = 0; jo < 8; jo++) oacc[jo] = (f32x4){0.f, 0.f, 0.f, 0.f};
    float lsum[4] = {0.f, 0.f, 0.f, 0.f};

    const float scale = 0.08838834764831845f;  // 1/sqrt(128)
    const float OFF = 4.0f;                    // static exp offset
    char* pbase = (char*)&plds[wid][0];
    int ntiles = q0 / 64 + 1;

    for (int t = 0; t < ntiles; t++) {
        int kv0 = t * 64;
        // ---- S = Q K^T for 16 x 64 tile ----
        f32x4 sC[4];
#pragma unroll
        for (int jt = 0; jt < 4; jt++) sC[jt] = (f32x4){0.f, 0.f, 0.f, 0.f};
#pragma unroll
        for (int kk = 0; kk < 4; kk++) {
#pragma unroll
            for (int jt = 0; jt < 4; jt++) {
                half8 bk = *reinterpret_cast<const half8*>(
                    kn + (size_t)(kv0 + jt * 16 + lr) * HD + kk * 32 + lg * 8);
                sC[jt] = __builtin_amdgcn_mfma_f32_16x16x32_f16(qa[kk], bk, sC[jt], 0, 0, 0);
            }
        }
        // ---- p = exp(s*scale - OFF), accumulate row-sum per lane, bounce via LDS ----
        bool diag = (t == ntiles - 1);
#pragma unroll
        for (int jt = 0; jt < 4; jt++) {
#pragma unroll
            for (int r = 0; r < 4; r++) {
                int row = lg * 4 + r;
                float p = __expf(sC[jt][r] * scale - OFF);
                if (diag && (kv0 + jt * 16 + lr > q0 + row)) p = 0.f;
                lsum[r] += p;
                int colb = (lr + 16 * jt) * 2;
                *(_Float16*)(pbase + row * 128 + (colb ^ ((row & 7) << 4))) = (_Float16)p;
            }
        }
        // ---- O += P V (P read back as A-fragments, swizzled) ----
#pragma unroll
        for (int kk2 = 0; kk2 < 2; kk2++) {
            int colb = kk2 * 64 + lg * 16;
            half8 pa = *(const half8*)(pbase + lr * 128 + (colb ^ ((lr & 7) << 4)));
#pragma unroll
            for (int jo = 0; jo < 8; jo++) {
                half8 bv = *reinterpret_cast<const half8*>(
                    vp + (size_t)(jo * 16 + lr) * L + kv0 + kk2 * 32 + lg * 8);
                oacc[jo] = __builtin_amdgcn_mfma_f32_16x16x32_f16(pa, bv, oacc[jo], 0, 0, 0);
            }
        }
    }

    // ---- single end-of-kernel row-sum reduction (16-lane groups) ----
#pragma unroll
    for (int r = 0; r < 4; r++) {
#pragma unroll
        for (int off = 1; off < 16; off <<= 1) lsum[r] += __shfl_xor(lsum[r], off);
    }

    // ---- epilogue: O /= l, store fp16 to [l][h*128+d] ----
#pragma unroll
    for (int jo = 0; jo < 8; jo++) {
#pragma unroll
        for (int r = 0; r < 4; r++) {
            int row = q0 + lg * 4 + r;
            int col = h * HD + jo * 16 + lr;
            out[(size_t)row * D + col] = (_Float16)(oacc[jo][r] / lsum[r]);
        }
    }
}

extern "C" void kernel_launch(void* const* d_in, const int* in_sizes, int n_in,
                              void* d_out, int out_size, void* d_ws, size_t ws_size,
                              hipStream_t stream) {
    const float* x = (const float*)d_in[0];
    const float* wqkv = (const float*)d_in[1];
    const float* wout = (const float*)d_in[2];
    // block_mask (d_in[3]) is tril(ones) == causal; handled analytically.

    _Float16* ws = (_Float16*)d_ws;
    _Float16* xh = ws;                                    // L*D
    _Float16* wqkvh = xh + (size_t)L * D;                 // 3*D*D
    _Float16* wouth = wqkvh + (size_t)3 * D * D;          // D*D
    _Float16* qkh = wouth + (size_t)D * D;                // 2*NH*L*HD
    _Float16* vth = qkh + (size_t)2 * NH * L * HD;        // NH*HD*L
    _Float16* aoh = vth + (size_t)NH * HD * L;            // L*D

    cvt_kernel<<<2048, 256, 0, stream>>>(x, xh, L * D / 4);
    cvt_kernel<<<2048, 256, 0, stream>>>(wqkv, wqkvh, 3 * D * D / 4);
    cvt_kernel<<<2048, 256, 0, stream>>>(wout, wouth, D * D / 4);

    gemm_nt<0><<<dim3(L / 128, 3 * D / 128), 256, 0, stream>>>(
        xh, wqkvh, nullptr, qkh, vth, L, 3 * D, D);

    norm_rope<<<2 * NH * L / 4, 256, 0, stream>>>(qkh);

    attn_kernel<<<dim3(L / 64, NH), 256, 0, stream>>>(qkh, vth, aoh);

    gemm_nt<1><<<dim3(L / 128, D / 128), 256, 0, stream>>>(
        aoh, wouth, (float*)d_out, nullptr, nullptr, L, D, D);
}

// Round 3
// 403.665 us; speedup vs baseline: 1.3721x; 1.3721x over previous
//
#include <hip/hip_runtime.h>

#define L 2048
#define D 2048
#define NH 16
#define HD 128

typedef __attribute__((ext_vector_type(8))) _Float16 half8;
typedef __attribute__((ext_vector_type(4))) float f32x4;

__device__ __forceinline__ void gload_lds16(const void* g, void* l) {
    __builtin_amdgcn_global_load_lds(
        (const __attribute__((address_space(1))) uint32_t*)g,
        (__attribute__((address_space(3))) uint32_t*)l, 16, 0, 0);
}

// ---------------- f32 -> fp16 convert ----------------
__global__ void cvt_kernel(const float* __restrict__ in, _Float16* __restrict__ out, int n4) {
    int idx = blockIdx.x * blockDim.x + threadIdx.x;
    int stride = gridDim.x * blockDim.x;
    for (int i = idx; i < n4; i += stride) {
        float4 v = reinterpret_cast<const float4*>(in)[i];
        union { _Float16 h[4]; uint2 u; } pk;
        pk.h[0] = (_Float16)v.x; pk.h[1] = (_Float16)v.y;
        pk.h[2] = (_Float16)v.z; pk.h[3] = (_Float16)v.w;
        reinterpret_cast<uint2*>(out)[i] = pk.u;
    }
}

// ---------------- NT GEMM: C[M][N] = A[M][K] * B[N][K]^T ----------------
// EPI 0: scatter qkv. q -> qk[0][h][l][d] linear; k -> qk[1][h][l][d^((l&7)<<3)]
//        (XOR-swizzled for attn LDS staging); v -> vt[h][d][l] linear.
// EPI 1: write f32 C row-major to Cout
template <int EPI>
__global__ __launch_bounds__(256) void gemm_nt(
    const _Float16* __restrict__ A, const _Float16* __restrict__ B,
    float* __restrict__ Cout, _Float16* __restrict__ qk, _Float16* __restrict__ vt,
    int M, int N, int K)
{
    int wid = threadIdx.x >> 6;
    int lane = threadIdx.x & 63;
    int wr = wid >> 1, wc = wid & 1;
    int m0 = blockIdx.x * 128 + wr * 64;
    int n0 = blockIdx.y * 128 + wc * 64;
    int lr = lane & 15;   // row/col within 16
    int lg = lane >> 4;   // group 0..3

    f32x4 acc[4][4];
#pragma unroll
    for (int i = 0; i < 4; i++)
#pragma unroll
        for (int j = 0; j < 4; j++)
            acc[i][j] = (f32x4){0.f, 0.f, 0.f, 0.f};

    for (int k0 = 0; k0 < K; k0 += 32) {
        int ko = k0 + lg * 8;
        half8 a[4], b[4];
#pragma unroll
        for (int i = 0; i < 4; i++)
            a[i] = *reinterpret_cast<const half8*>(A + (size_t)(m0 + i * 16 + lr) * K + ko);
#pragma unroll
        for (int j = 0; j < 4; j++)
            b[j] = *reinterpret_cast<const half8*>(B + (size_t)(n0 + j * 16 + lr) * K + ko);
#pragma unroll
        for (int i = 0; i < 4; i++)
#pragma unroll
            for (int j = 0; j < 4; j++)
                acc[i][j] = __builtin_amdgcn_mfma_f32_16x16x32_f16(a[i], b[j], acc[i][j], 0, 0, 0);
    }

#pragma unroll
    for (int i = 0; i < 4; i++) {
#pragma unroll
        for (int j = 0; j < 4; j++) {
#pragma unroll
            for (int r = 0; r < 4; r++) {
                int row = m0 + i * 16 + lg * 4 + r;  // C layout: row=(lane>>4)*4+reg
                int col = n0 + j * 16 + lr;          //           col=lane&15
                float v = acc[i][j][r];
                if (EPI == 0) {
                    int t = col >> 11;
                    int w2 = col & 2047;
                    int h = w2 >> 7, d = w2 & 127;
                    if (t == 0) {
                        qk[(((size_t)h) * L + row) * HD + d] = (_Float16)v;
                    } else if (t == 1) {
                        int dsw = d ^ ((row & 7) << 3);   // pre-swizzle for attn K staging
                        qk[(((size_t)NH + h) * L + row) * HD + dsw] = (_Float16)v;
                    } else {
                        vt[((size_t)h * HD + d) * L + row] = (_Float16)v;
                    }
                } else {
                    Cout[(size_t)row * N + col] = v;
                }
            }
        }
    }
}

// ---------------- fused RMSNorm + RoPE on q and k planes (in place) ----------------
// k plane is stored element-swizzled (d' = d ^ ((l&7)<<3)); RMS sum is
// permutation-invariant and RoPE pairs stay adjacent, so only the pair
// index used for the frequency changes: i = lane ^ ((l&7)<<2).
__global__ void norm_rope(_Float16* __restrict__ qk) {
    int wid = threadIdx.x >> 6, lane = threadIdx.x & 63;
    int row = blockIdx.x * 4 + wid;      // 0 .. 2*NH*L-1
    int l = row & (L - 1);
    int th = row >> 11;                  // t*NH + h, 0..31
    _Float16* p = qk + ((size_t)th * L + l) * HD + lane * 2;
    float x0 = (float)p[0];
    float x1 = (float)p[1];
    float ss = x0 * x0 + x1 * x1;
#pragma unroll
    for (int off = 1; off < 64; off <<= 1) ss += __shfl_xor(ss, off);
    float r = rsqrtf(ss * (1.0f / 128.0f) + 1e-5f);
    float n0 = x0 * r, n1 = x1 * r;
    int i = (th >= NH) ? (lane ^ ((l & 7) << 2)) : lane;   // swizzle-aware pair index
    float freq = expf(-(float)(2 * i) * (1.0f / 128.0f) * logf(100000.0f));
    float ang = (float)l * freq;
    float s, c;
    sincosf(ang, &s, &c);
    p[0] = (_Float16)(n1 * c - n0 * s);
    p[1] = (_Float16)(n1 * s + n0 * c);
}

// ---------------- causal flash attention, v3 ----------------
// K staged in LDS via global_load_lds, double-buffered 2-phase pipeline
// (stage t+1 issued before compute of t). K stored pre-swizzled in global;
// ds_read applies the same XOR -> conflict-free. V prefetched to registers
// at tile start. Static-offset softmax (no max tracking, no in-loop shfl).
// grid (L/64, NH), block 256 (4 waves); all 4 waves share KV tiles.
__global__ __launch_bounds__(256, 2) void attn_kernel(
    const _Float16* __restrict__ qk, const _Float16* __restrict__ vt,
    _Float16* __restrict__ out)
{
    __shared__ __align__(16) _Float16 Kt[2][64 * HD];     // 2 x 16 KB
    __shared__ __align__(16) _Float16 plds[4][16 * 64];   // 8 KB
    int wid = threadIdx.x >> 6, lane = threadIdx.x & 63;
    int h = blockIdx.y;
    int qt = gridDim.x - 1 - blockIdx.x;   // heavy q-tiles launch first
    int q0 = qt * 64 + wid * 16;
    int lr = lane & 15, lg = lane >> 4;

    const _Float16* qn = qk + (size_t)h * L * HD;              // q plane
    const _Float16* kn = qk + ((size_t)(NH + h) * L) * HD;     // k plane (swizzled)
    const _Float16* vp = vt + (size_t)h * HD * L;              // v^T plane

    half8 qa[4];
#pragma unroll
    for (int kk = 0; kk < 4; kk++)
        qa[kk] = *reinterpret_cast<const half8*>(qn + (size_t)(q0 + lr) * HD + kk * 32 + lg * 8);

    f32x4 oacc[8];
#pragma unroll
    for (int jo = 0; jo < 8; jo++) oacc[jo] = (f32x4){0.f, 0.f, 0.f, 0.f};
    float lsum[4] = {0.f, 0.f, 0.f, 0.f};

    const float scale = 0.08838834764831845f;  // 1/sqrt(128)
    const float OFF = 4.0f;                    // static exp offset
    char* pbase = (char*)&plds[wid][0];
    int nt = qt + 1;                           // uniform across waves (barrier-safe)

    // ---- stage K tile t into buffer b (16 KB contiguous copy, wave w: 4 KB) ----
    auto stage_k = [&](int t, int b) {
        const char* src = (const char*)(kn + (size_t)t * 64 * HD) + wid * 4096 + lane * 16;
        char* dst = (char*)&Kt[b][0] + wid * 4096;
#pragma unroll
        for (int i = 0; i < 4; i++)
            gload_lds16(src + i * 1024, dst + i * 1024);
    };

    stage_k(0, 0);
    __syncthreads();

    for (int t = 0; t < nt; t++) {
        int cur = t & 1;
        if (t + 1 < nt) stage_k(t + 1, cur ^ 1);
        int kv0 = t * 64;

        // ---- V prefetch to registers (consumed ~end of tile) ----
        half8 vr0[8], vr1[8];
#pragma unroll
        for (int jo = 0; jo < 8; jo++) {
            const _Float16* vrow = vp + (size_t)(jo * 16 + lr) * L + kv0 + lg * 8;
            vr0[jo] = *reinterpret_cast<const half8*>(vrow);
            vr1[jo] = *reinterpret_cast<const half8*>(vrow + 32);
        }

        // ---- S = Q K^T from LDS (swizzled ds_read_b128) ----
        f32x4 sC[4];
#pragma unroll
        for (int jt = 0; jt < 4; jt++) sC[jt] = (f32x4){0.f, 0.f, 0.f, 0.f};
        const char* kb = (const char*)&Kt[cur][0];
#pragma unroll
        for (int kk = 0; kk < 4; kk++) {
#pragma unroll
            for (int jt = 0; jt < 4; jt++) {
                half8 bk = *(const half8*)(kb + (jt * 16 + lr) * 256 +
                                           ((kk * 64 + lg * 16) ^ ((lr & 7) << 4)));
                sC[jt] = __builtin_amdgcn_mfma_f32_16x16x32_f16(qa[kk], bk, sC[jt], 0, 0, 0);
            }
        }

        // ---- p = exp(s*scale - OFF), row-sum per lane, bounce via LDS ----
        bool diag = (t == nt - 1);
#pragma unroll
        for (int jt = 0; jt < 4; jt++) {
#pragma unroll
            for (int r = 0; r < 4; r++) {
                int row = lg * 4 + r;
                float p = __expf(sC[jt][r] * scale - OFF);
                if (diag && (kv0 + jt * 16 + lr > q0 + row)) p = 0.f;
                lsum[r] += p;
                int colb = (lr + 16 * jt) * 2;
                *(_Float16*)(pbase + row * 128 + (colb ^ ((row & 7) << 4))) = (_Float16)p;
            }
        }

        // ---- O += P V ----
#pragma unroll
        for (int kk2 = 0; kk2 < 2; kk2++) {
            half8 pa = *(const half8*)(pbase + lr * 128 +
                                       ((kk2 * 64 + lg * 16) ^ ((lr & 7) << 4)));
#pragma unroll
            for (int jo = 0; jo < 8; jo++) {
                half8 bv = (kk2 == 0) ? vr0[jo] : vr1[jo];
                oacc[jo] = __builtin_amdgcn_mfma_f32_16x16x32_f16(pa, bv, oacc[jo], 0, 0, 0);
            }
        }
        __syncthreads();
    }

    // ---- single end-of-kernel row-sum reduction (16-lane groups) ----
#pragma unroll
    for (int r = 0; r < 4; r++) {
#pragma unroll
        for (int off = 1; off < 16; off <<= 1) lsum[r] += __shfl_xor(lsum[r], off);
    }

    // ---- epilogue: O /= l, store fp16 to [l][h*128+d] ----
#pragma unroll
    for (int jo = 0; jo < 8; jo++) {
#pragma unroll
        for (int r = 0; r < 4; r++) {
            int row = q0 + lg * 4 + r;
            int col = h * HD + jo * 16 + lr;
            out[(size_t)row * D + col] = (_Float16)(oacc[jo][r] / lsum[r]);
        }
    }
}

extern "C" void kernel_launch(void* const* d_in, const int* in_sizes, int n_in,
                              void* d_out, int out_size, void* d_ws, size_t ws_size,
                              hipStream_t stream) {
    const float* x = (const float*)d_in[0];
    const float* wqkv = (const float*)d_in[1];
    const float* wout = (const float*)d_in[2];
    // block_mask (d_in[3]) is tril(ones) == causal; handled analytically.

    _Float16* ws = (_Float16*)d_ws;
    _Float16* xh = ws;                                    // L*D
    _Float16* wqkvh = xh + (size_t)L * D;                 // 3*D*D
    _Float16* wouth = wqkvh + (size_t)3 * D * D;          // D*D
    _Float16* qkh = wouth + (size_t)D * D;                // 2*NH*L*HD
    _Float16* vth = qkh + (size_t)2 * NH * L * HD;        // NH*HD*L
    _Float16* aoh = vth + (size_t)NH * HD * L;            // L*D

    cvt_kernel<<<2048, 256, 0, stream>>>(x, xh, L * D / 4);
    cvt_kernel<<<2048, 256, 0, stream>>>(wqkv, wqkvh, 3 * D * D / 4);
    cvt_kernel<<<2048, 256, 0, stream>>>(wout, wouth, D * D / 4);

    gemm_nt<0><<<dim3(L / 128, 3 * D / 128), 256, 0, stream>>>(
        xh, wqkvh, nullptr, qkh, vth, L, 3 * D, D);

    norm_rope<<<2 * NH * L / 4, 256, 0, stream>>>(qkh);

    attn_kernel<<<dim3(L / 64, NH), 256, 0, stream>>>(qkh, vth, aoh);

    gemm_nt<1><<<dim3(L / 128, D / 128), 256, 0, stream>>>(
        aoh, wouth, (float*)d_out, nullptr, nullptr, L, D, D);
}

// Round 4
// 271.002 us; speedup vs baseline: 2.0438x; 1.4895x over previous
//
#include <hip/hip_runtime.h>

#define L 2048
#define D 2048
#define NH 16
#define HD 128

typedef __attribute__((ext_vector_type(8))) _Float16 half8;
typedef __attribute__((ext_vector_type(4))) float f32x4;

__device__ __forceinline__ void gload_lds16(const void* g, void* l) {
    __builtin_amdgcn_global_load_lds(
        (const __attribute__((address_space(1))) uint32_t*)g,
        (__attribute__((address_space(3))) uint32_t*)l, 16, 0, 0);
}

// ---------------- f32 -> fp16 convert ----------------
__global__ void cvt_kernel(const float* __restrict__ in, _Float16* __restrict__ out, int n4) {
    int idx = blockIdx.x * blockDim.x + threadIdx.x;
    int stride = gridDim.x * blockDim.x;
    for (int i = idx; i < n4; i += stride) {
        float4 v = reinterpret_cast<const float4*>(in)[i];
        union { _Float16 h[4]; uint2 u; } pk;
        pk.h[0] = (_Float16)v.x; pk.h[1] = (_Float16)v.y;
        pk.h[2] = (_Float16)v.z; pk.h[3] = (_Float16)v.w;
        reinterpret_cast<uint2*>(out)[i] = pk.u;
    }
}

// ---------------- NT GEMM: C[M][N] = A[M][K] * B[N][K]^T ----------------
// LDS-staged (global_load_lds w=16), double-buffered, 2-phase pipeline:
// STAGE(t+1) issued before compute(t), one vmcnt(0)+barrier per K-step.
// 128x128 block tile, 4 waves 2x2, 4x4 16x16x32 fragments per wave, BK=32.
// EPI 0: scatter qkv. q -> qk[0][h][l][d] linear; k -> qk[1][h][l][d^((l&7)<<3)]
//        (XOR-swizzled for attn LDS staging); v -> vt[h][d][l] linear.
// EPI 1: write f32 C row-major to Cout
template <int EPI>
__global__ __launch_bounds__(256) void gemm_nt(
    const _Float16* __restrict__ A, const _Float16* __restrict__ B,
    float* __restrict__ Cout, _Float16* __restrict__ qk, _Float16* __restrict__ vt,
    int M, int N, int K)
{
    __shared__ __align__(16) _Float16 Asm[2][128 * 32];   // 2 x 8 KB
    __shared__ __align__(16) _Float16 Bsm[2][128 * 32];   // 2 x 8 KB
    int tid = threadIdx.x;
    int wid = tid >> 6;
    int lane = tid & 63;
    int wr = wid >> 1, wc = wid & 1;
    int m0 = blockIdx.x * 128;
    int n0 = blockIdx.y * 128;
    int lr = lane & 15;   // row/col within 16
    int lg = lane >> 4;   // group 0..3

    // staging source: thread tid covers tile rows {tid>>2, 64+(tid>>2)}, byte col (tid&3)*16
    const char* Asrc = (const char*)(A + (size_t)(m0 + (tid >> 2)) * K) + (tid & 3) * 16;
    const char* Bsrc = (const char*)(B + (size_t)(n0 + (tid >> 2)) * K) + (tid & 3) * 16;
    size_t rowskip = (size_t)64 * K * 2;   // 64 rows of source, bytes

    auto stage = [&](int k0, int b) {
        const char* as = Asrc + (size_t)k0 * 2;
        const char* bs = Bsrc + (size_t)k0 * 2;
        char* ad = (char*)&Asm[b][0] + wid * 1024;   // + lane*16 by hardware
        char* bd = (char*)&Bsm[b][0] + wid * 1024;
        gload_lds16(as, ad);
        gload_lds16(as + rowskip, ad + 4096);
        gload_lds16(bs, bd);
        gload_lds16(bs + rowskip, bd + 4096);
    };

    f32x4 acc[4][4];
#pragma unroll
    for (int i = 0; i < 4; i++)
#pragma unroll
        for (int j = 0; j < 4; j++)
            acc[i][j] = (f32x4){0.f, 0.f, 0.f, 0.f};

    int NT = K / 32;
    stage(0, 0);
    asm volatile("s_waitcnt vmcnt(0)" ::: "memory");
    __syncthreads();

    for (int t = 0; t < NT; t++) {
        int cur = t & 1;
        if (t + 1 < NT) stage((t + 1) * 32, cur ^ 1);

        const char* ab = (const char*)&Asm[cur][0] + (wr * 64 + lr) * 64 + lg * 16;
        const char* bb = (const char*)&Bsm[cur][0] + (wc * 64 + lr) * 64 + lg * 16;
        half8 a[4], b[4];
#pragma unroll
        for (int i = 0; i < 4; i++) a[i] = *(const half8*)(ab + i * 1024);
#pragma unroll
        for (int j = 0; j < 4; j++) b[j] = *(const half8*)(bb + j * 1024);
#pragma unroll
        for (int i = 0; i < 4; i++)
#pragma unroll
            for (int j = 0; j < 4; j++)
                acc[i][j] = __builtin_amdgcn_mfma_f32_16x16x32_f16(a[i], b[j], acc[i][j], 0, 0, 0);

        asm volatile("s_waitcnt vmcnt(0)" ::: "memory");
        __syncthreads();
    }

#pragma unroll
    for (int i = 0; i < 4; i++) {
#pragma unroll
        for (int j = 0; j < 4; j++) {
#pragma unroll
            for (int r = 0; r < 4; r++) {
                int row = m0 + wr * 64 + i * 16 + lg * 4 + r;  // C layout: row=(lane>>4)*4+reg
                int col = n0 + wc * 64 + j * 16 + lr;          //           col=lane&15
                float v = acc[i][j][r];
                if (EPI == 0) {
                    int t = col >> 11;
                    int w2 = col & 2047;
                    int h = w2 >> 7, d = w2 & 127;
                    if (t == 0) {
                        qk[(((size_t)h) * L + row) * HD + d] = (_Float16)v;
                    } else if (t == 1) {
                        int dsw = d ^ ((row & 7) << 3);   // pre-swizzle for attn K staging
                        qk[(((size_t)NH + h) * L + row) * HD + dsw] = (_Float16)v;
                    } else {
                        vt[((size_t)h * HD + d) * L + row] = (_Float16)v;
                    }
                } else {
                    Cout[(size_t)row * N + col] = v;
                }
            }
        }
    }
}

// ---------------- fused RMSNorm + RoPE on q and k planes (in place) ----------------
// k plane is stored element-swizzled (d' = d ^ ((l&7)<<3)); RMS sum is
// permutation-invariant and RoPE pairs stay adjacent, so only the pair
// index used for the frequency changes: i = lane ^ ((l&7)<<2).
__global__ void norm_rope(_Float16* __restrict__ qk) {
    int wid = threadIdx.x >> 6, lane = threadIdx.x & 63;
    int row = blockIdx.x * 4 + wid;      // 0 .. 2*NH*L-1
    int l = row & (L - 1);
    int th = row >> 11;                  // t*NH + h, 0..31
    _Float16* p = qk + ((size_t)th * L + l) * HD + lane * 2;
    float x0 = (float)p[0];
    float x1 = (float)p[1];
    float ss = x0 * x0 + x1 * x1;
#pragma unroll
    for (int off = 1; off < 64; off <<= 1) ss += __shfl_xor(ss, off);
    float r = rsqrtf(ss * (1.0f / 128.0f) + 1e-5f);
    float n0 = x0 * r, n1 = x1 * r;
    int i = (th >= NH) ? (lane ^ ((l & 7) << 2)) : lane;   // swizzle-aware pair index
    float freq = expf(-(float)(2 * i) * (1.0f / 128.0f) * logf(100000.0f));
    float ang = (float)l * freq;
    float s, c;
    sincosf(ang, &s, &c);
    p[0] = (_Float16)(n1 * c - n0 * s);
    p[1] = (_Float16)(n1 * s + n0 * c);
}

// ---------------- causal flash attention, v3 ----------------
// K staged in LDS via global_load_lds, double-buffered 2-phase pipeline
// (stage t+1 issued before compute of t). K stored pre-swizzled in global;
// ds_read applies the same XOR -> conflict-free. V prefetched to registers
// at tile start. Static-offset softmax (no max tracking, no in-loop shfl).
// grid (L/64, NH), block 256 (4 waves); all 4 waves share KV tiles.
__global__ __launch_bounds__(256, 2) void attn_kernel(
    const _Float16* __restrict__ qk, const _Float16* __restrict__ vt,
    _Float16* __restrict__ out)
{
    __shared__ __align__(16) _Float16 Kt[2][64 * HD];     // 2 x 16 KB
    __shared__ __align__(16) _Float16 plds[4][16 * 64];   // 8 KB
    int wid = threadIdx.x >> 6, lane = threadIdx.x & 63;
    int h = blockIdx.y;
    int qt = gridDim.x - 1 - blockIdx.x;   // heavy q-tiles launch first
    int q0 = qt * 64 + wid * 16;
    int lr = lane & 15, lg = lane >> 4;

    const _Float16* qn = qk + (size_t)h * L * HD;              // q plane
    const _Float16* kn = qk + ((size_t)(NH + h) * L) * HD;     // k plane (swizzled)
    const _Float16* vp = vt + (size_t)h * HD * L;              // v^T plane

    half8 qa[4];
#pragma unroll
    for (int kk = 0; kk < 4; kk++)
        qa[kk] = *reinterpret_cast<const half8*>(qn + (size_t)(q0 + lr) * HD + kk * 32 + lg * 8);

    f32x4 oacc[8];
#pragma unroll
    for (int jo = 0; jo < 8; jo++) oacc[jo] = (f32x4){0.f, 0.f, 0.f, 0.f};
    float lsum[4] = {0.f, 0.f, 0.f, 0.f};

    const float scale = 0.08838834764831845f;  // 1/sqrt(128)
    const float OFF = 4.0f;                    // static exp offset
    char* pbase = (char*)&plds[wid][0];
    int nt = qt + 1;                           // uniform across waves (barrier-safe)

    // ---- stage K tile t into buffer b (16 KB contiguous copy, wave w: 4 KB) ----
    auto stage_k = [&](int t, int b) {
        const char* src = (const char*)(kn + (size_t)t * 64 * HD) + wid * 4096 + lane * 16;
        char* dst = (char*)&Kt[b][0] + wid * 4096;
#pragma unroll
        for (int i = 0; i < 4; i++)
            gload_lds16(src + i * 1024, dst + i * 1024);
    };

    stage_k(0, 0);
    __syncthreads();

    for (int t = 0; t < nt; t++) {
        int cur = t & 1;
        if (t + 1 < nt) stage_k(t + 1, cur ^ 1);
        int kv0 = t * 64;

        // ---- V prefetch to registers (consumed ~end of tile) ----
        half8 vr0[8], vr1[8];
#pragma unroll
        for (int jo = 0; jo < 8; jo++) {
            const _Float16* vrow = vp + (size_t)(jo * 16 + lr) * L + kv0 + lg * 8;
            vr0[jo] = *reinterpret_cast<const half8*>(vrow);
            vr1[jo] = *reinterpret_cast<const half8*>(vrow + 32);
        }

        // ---- S = Q K^T from LDS (swizzled ds_read_b128) ----
        f32x4 sC[4];
#pragma unroll
        for (int jt = 0; jt < 4; jt++) sC[jt] = (f32x4){0.f, 0.f, 0.f, 0.f};
        const char* kb = (const char*)&Kt[cur][0];
#pragma unroll
        for (int kk = 0; kk < 4; kk++) {
#pragma unroll
            for (int jt = 0; jt < 4; jt++) {
                half8 bk = *(const half8*)(kb + (jt * 16 + lr) * 256 +
                                           ((kk * 64 + lg * 16) ^ ((lr & 7) << 4)));
                sC[jt] = __builtin_amdgcn_mfma_f32_16x16x32_f16(qa[kk], bk, sC[jt], 0, 0, 0);
            }
        }

        // ---- p = exp(s*scale - OFF), row-sum per lane, bounce via LDS ----
        bool diag = (t == nt - 1);
#pragma unroll
        for (int jt = 0; jt < 4; jt++) {
#pragma unroll
            for (int r = 0; r < 4; r++) {
                int row = lg * 4 + r;
                float p = __expf(sC[jt][r] * scale - OFF);
                if (diag && (kv0 + jt * 16 + lr > q0 + row)) p = 0.f;
                lsum[r] += p;
                int colb = (lr + 16 * jt) * 2;
                *(_Float16*)(pbase + row * 128 + (colb ^ ((row & 7) << 4))) = (_Float16)p;
            }
        }

        // ---- O += P V ----
#pragma unroll
        for (int kk2 = 0; kk2 < 2; kk2++) {
            half8 pa = *(const half8*)(pbase + lr * 128 +
                                       ((kk2 * 64 + lg * 16) ^ ((lr & 7) << 4)));
#pragma unroll
            for (int jo = 0; jo < 8; jo++) {
                half8 bv = (kk2 == 0) ? vr0[jo] : vr1[jo];
                oacc[jo] = __builtin_amdgcn_mfma_f32_16x16x32_f16(pa, bv, oacc[jo], 0, 0, 0);
            }
        }
        __syncthreads();
    }

    // ---- single end-of-kernel row-sum reduction (16-lane groups) ----
#pragma unroll
    for (int r = 0; r < 4; r++) {
#pragma unroll
        for (int off = 1; off < 16; off <<= 1) lsum[r] += __shfl_xor(lsum[r], off);
    }

    // ---- epilogue: O /= l, store fp16 to [l][h*128+d] ----
#pragma unroll
    for (int jo = 0; jo < 8; jo++) {
#pragma unroll
        for (int r = 0; r < 4; r++) {
            int row = q0 + lg * 4 + r;
            int col = h * HD + jo * 16 + lr;
            out[(size_t)row * D + col] = (_Float16)(oacc[jo][r] / lsum[r]);
        }
    }
}

extern "C" void kernel_launch(void* const* d_in, const int* in_sizes, int n_in,
                              void* d_out, int out_size, void* d_ws, size_t ws_size,
                              hipStream_t stream) {
    const float* x = (const float*)d_in[0];
    const float* wqkv = (const float*)d_in[1];
    const float* wout = (const float*)d_in[2];
    // block_mask (d_in[3]) is tril(ones) == causal; handled analytically.

    _Float16* ws = (_Float16*)d_ws;
    _Float16* xh = ws;                                    // L*D
    _Float16* wqkvh = xh + (size_t)L * D;                 // 3*D*D
    _Float16* wouth = wqkvh + (size_t)3 * D * D;          // D*D
    _Float16* qkh = wouth + (size_t)D * D;                // 2*NH*L*HD
    _Float16* vth = qkh + (size_t)2 * NH * L * HD;        // NH*HD*L
    _Float16* aoh = vth + (size_t)NH * HD * L;            // L*D

    cvt_kernel<<<2048, 256, 0, stream>>>(x, xh, L * D / 4);
    cvt_kernel<<<2048, 256, 0, stream>>>(wqkv, wqkvh, 3 * D * D / 4);
    cvt_kernel<<<2048, 256, 0, stream>>>(wout, wouth, D * D / 4);

    gemm_nt<0><<<dim3(L / 128, 3 * D / 128), 256, 0, stream>>>(
        xh, wqkvh, nullptr, qkh, vth, L, 3 * D, D);

    norm_rope<<<2 * NH * L / 4, 256, 0, stream>>>(qkh);

    attn_kernel<<<dim3(L / 64, NH), 256, 0, stream>>>(qkh, vth, aoh);

    gemm_nt<1><<<dim3(L / 128, D / 128), 256, 0, stream>>>(
        aoh, wouth, (float*)d_out, nullptr, nullptr, L, D, D);
}

// Round 5
// 240.037 us; speedup vs baseline: 2.3074x; 1.1290x over previous
//
#include <hip/hip_runtime.h>

#define L 2048
#define D 2048
#define NH 16
#define HD 128

typedef __attribute__((ext_vector_type(8))) _Float16 half8;
typedef __attribute__((ext_vector_type(4))) float f32x4;

__device__ __forceinline__ void gload_lds16(const void* g, void* l) {
    __builtin_amdgcn_global_load_lds(
        (const __attribute__((address_space(1))) uint32_t*)g,
        (__attribute__((address_space(3))) uint32_t*)l, 16, 0, 0);
}

// ---------------- f32 -> fp16 convert ----------------
__global__ void cvt_kernel(const float* __restrict__ in, _Float16* __restrict__ out, int n4) {
    int idx = blockIdx.x * blockDim.x + threadIdx.x;
    int stride = gridDim.x * blockDim.x;
    for (int i = idx; i < n4; i += stride) {
        float4 v = reinterpret_cast<const float4*>(in)[i];
        union { _Float16 h[4]; uint2 u; } pk;
        pk.h[0] = (_Float16)v.x; pk.h[1] = (_Float16)v.y;
        pk.h[2] = (_Float16)v.z; pk.h[3] = (_Float16)v.w;
        reinterpret_cast<uint2*>(out)[i] = pk.u;
    }
}

// ---------------- NT GEMM: C[M][N] = A[M][K] * B[N][K]^T ----------------
// LDS-staged (global_load_lds w=16), double-buffered, 2-phase pipeline.
// 128x128 block tile, 4 waves 2x2, 4x4 16x16x32 fragments per wave, BK=32.
// EPI 0: scatter qkv. q -> qk[0][h][l][d] linear; k -> qk[1][h][l][d^((l&7)<<3)]
//        (XOR-swizzled for attn LDS staging); v -> vt[h][d][l] linear.
// EPI 1: write f32 C row-major to Cout
template <int EPI>
__global__ __launch_bounds__(256) void gemm_nt(
    const _Float16* __restrict__ A, const _Float16* __restrict__ B,
    float* __restrict__ Cout, _Float16* __restrict__ qk, _Float16* __restrict__ vt,
    int M, int N, int K)
{
    __shared__ __align__(16) _Float16 Asm[2][128 * 32];   // 2 x 8 KB
    __shared__ __align__(16) _Float16 Bsm[2][128 * 32];   // 2 x 8 KB
    int tid = threadIdx.x;
    int wid = tid >> 6;
    int lane = tid & 63;
    int wr = wid >> 1, wc = wid & 1;
    int m0 = blockIdx.x * 128;
    int n0 = blockIdx.y * 128;
    int lr = lane & 15;   // row/col within 16
    int lg = lane >> 4;   // group 0..3

    // staging source: thread tid covers tile rows {tid>>2, 64+(tid>>2)}, byte col (tid&3)*16
    const char* Asrc = (const char*)(A + (size_t)(m0 + (tid >> 2)) * K) + (tid & 3) * 16;
    const char* Bsrc = (const char*)(B + (size_t)(n0 + (tid >> 2)) * K) + (tid & 3) * 16;
    size_t rowskip = (size_t)64 * K * 2;   // 64 rows of source, bytes

    auto stage = [&](int k0, int b) {
        const char* as = Asrc + (size_t)k0 * 2;
        const char* bs = Bsrc + (size_t)k0 * 2;
        char* ad = (char*)&Asm[b][0] + wid * 1024;   // + lane*16 by hardware
        char* bd = (char*)&Bsm[b][0] + wid * 1024;
        gload_lds16(as, ad);
        gload_lds16(as + rowskip, ad + 4096);
        gload_lds16(bs, bd);
        gload_lds16(bs + rowskip, bd + 4096);
    };

    f32x4 acc[4][4];
#pragma unroll
    for (int i = 0; i < 4; i++)
#pragma unroll
        for (int j = 0; j < 4; j++)
            acc[i][j] = (f32x4){0.f, 0.f, 0.f, 0.f};

    int NT = K / 32;
    stage(0, 0);
    asm volatile("s_waitcnt vmcnt(0)" ::: "memory");
    __syncthreads();

    for (int t = 0; t < NT; t++) {
        int cur = t & 1;
        if (t + 1 < NT) stage((t + 1) * 32, cur ^ 1);

        const char* ab = (const char*)&Asm[cur][0] + (wr * 64 + lr) * 64 + lg * 16;
        const char* bb = (const char*)&Bsm[cur][0] + (wc * 64 + lr) * 64 + lg * 16;
        half8 a[4], b[4];
#pragma unroll
        for (int i = 0; i < 4; i++) a[i] = *(const half8*)(ab + i * 1024);
#pragma unroll
        for (int j = 0; j < 4; j++) b[j] = *(const half8*)(bb + j * 1024);
#pragma unroll
        for (int i = 0; i < 4; i++)
#pragma unroll
            for (int j = 0; j < 4; j++)
                acc[i][j] = __builtin_amdgcn_mfma_f32_16x16x32_f16(a[i], b[j], acc[i][j], 0, 0, 0);

        asm volatile("s_waitcnt vmcnt(0)" ::: "memory");
        __syncthreads();
    }

#pragma unroll
    for (int i = 0; i < 4; i++) {
#pragma unroll
        for (int j = 0; j < 4; j++) {
#pragma unroll
            for (int r = 0; r < 4; r++) {
                int row = m0 + wr * 64 + i * 16 + lg * 4 + r;  // C layout: row=(lane>>4)*4+reg
                int col = n0 + wc * 64 + j * 16 + lr;          //           col=lane&15
                float v = acc[i][j][r];
                if (EPI == 0) {
                    int t = col >> 11;
                    int w2 = col & 2047;
                    int h = w2 >> 7, d = w2 & 127;
                    if (t == 0) {
                        qk[(((size_t)h) * L + row) * HD + d] = (_Float16)v;
                    } else if (t == 1) {
                        int dsw = d ^ ((row & 7) << 3);   // pre-swizzle for attn K staging
                        qk[(((size_t)NH + h) * L + row) * HD + dsw] = (_Float16)v;
                    } else {
                        vt[((size_t)h * HD + d) * L + row] = (_Float16)v;
                    }
                } else {
                    Cout[(size_t)row * N + col] = v;
                }
            }
        }
    }
}

// ---------------- fused RMSNorm + RoPE on q and k planes (in place) ----------------
// k plane is stored element-swizzled (d' = d ^ ((l&7)<<3)); RMS sum is
// permutation-invariant and RoPE pairs stay adjacent, so only the pair
// index used for the frequency changes: i = lane ^ ((l&7)<<2).
__global__ void norm_rope(_Float16* __restrict__ qk) {
    int wid = threadIdx.x >> 6, lane = threadIdx.x & 63;
    int row = blockIdx.x * 4 + wid;      // 0 .. 2*NH*L-1
    int l = row & (L - 1);
    int th = row >> 11;                  // t*NH + h, 0..31
    _Float16* p = qk + ((size_t)th * L + l) * HD + lane * 2;
    float x0 = (float)p[0];
    float x1 = (float)p[1];
    float ss = x0 * x0 + x1 * x1;
#pragma unroll
    for (int off = 1; off < 64; off <<= 1) ss += __shfl_xor(ss, off);
    float r = rsqrtf(ss * (1.0f / 128.0f) + 1e-5f);
    float n0 = x0 * r, n1 = x1 * r;
    int i = (th >= NH) ? (lane ^ ((l & 7) << 2)) : lane;   // swizzle-aware pair index
    float freq = expf(-(float)(2 * i) * (1.0f / 128.0f) * logf(100000.0f));
    float ang = (float)l * freq;
    float s, c;
    sincosf(ang, &s, &c);
    p[0] = (_Float16)(n1 * c - n0 * s);
    p[1] = (_Float16)(n1 * s + n0 * c);
}

// ---------------- causal flash attention, v4 ----------------
// Changes vs v3:
//  (1) 1-D grid 512 with complementary work pairing: bid and bid+256 map to
//      qt = g and 31-g, so each CU's two resident blocks total 33 tiles
//      (v3's 2-D grid paired SAME-weight blocks on each CU -> 12% occupancy).
//  (2) V register loads issued FIRST each tile, order pinned by
//      sched_barrier(0), stage issued after. PV then waits vmcnt(4) instead
//      of vmcnt(0) -> the K-stage DMA stays in flight through the whole tile.
// grid 512 x 1, block 256 (4 waves). Wave w owns q rows qt*64 + w*16.
__global__ __launch_bounds__(256, 2) void attn_kernel(
    const _Float16* __restrict__ qk, const _Float16* __restrict__ vt,
    _Float16* __restrict__ out)
{
    __shared__ __align__(16) _Float16 Kt[2][64 * HD];     // 2 x 16 KB
    __shared__ __align__(16) _Float16 plds[4][16 * 64];   // 8 KB
    int wid = threadIdx.x >> 6, lane = threadIdx.x & 63;
    int bid = blockIdx.x;
    int p5 = bid & 255;
    int h = p5 & 15;
    int g = p5 >> 4;
    int qt = (bid < 256) ? g : (31 - g);   // complementary pairing
    int q0 = qt * 64 + wid * 16;
    int lr = lane & 15, lg = lane >> 4;

    const _Float16* qn = qk + (size_t)h * L * HD;              // q plane
    const _Float16* kn = qk + ((size_t)(NH + h) * L) * HD;     // k plane (swizzled)
    const _Float16* vp = vt + (size_t)h * HD * L;              // v^T plane

    half8 qa[4];
#pragma unroll
    for (int kk = 0; kk < 4; kk++)
        qa[kk] = *reinterpret_cast<const half8*>(qn + (size_t)(q0 + lr) * HD + kk * 32 + lg * 8);

    f32x4 oacc[8];
#pragma unroll
    for (int jo = 0; jo < 8; jo++) oacc[jo] = (f32x4){0.f, 0.f, 0.f, 0.f};
    float lsum[4] = {0.f, 0.f, 0.f, 0.f};

    const float scale = 0.08838834764831845f;  // 1/sqrt(128)
    const float OFF = 4.0f;                    // static exp offset
    char* pbase = (char*)&plds[wid][0];
    int nt = qt + 1;                           // uniform across waves (barrier-safe)

    // ---- stage K tile t into buffer b (16 KB contiguous copy, wave w: 4 KB) ----
    auto stage_k = [&](int t, int b) {
        const char* src = (const char*)(kn + (size_t)t * 64 * HD) + wid * 4096 + lane * 16;
        char* dst = (char*)&Kt[b][0] + wid * 4096;
#pragma unroll
        for (int i = 0; i < 4; i++)
            gload_lds16(src + i * 1024, dst + i * 1024);
    };

    stage_k(0, 0);
    __syncthreads();

    for (int t = 0; t < nt; t++) {
        int cur = t & 1;
        int kv0 = t * 64;

        // ---- (1) V register loads FIRST (oldest in vmcnt queue) ----
        half8 vr0[8], vr1[8];
#pragma unroll
        for (int jo = 0; jo < 8; jo++) {
            const _Float16* vrow = vp + (size_t)(jo * 16 + lr) * L + kv0 + lg * 8;
            vr0[jo] = *reinterpret_cast<const half8*>(vrow);
            vr1[jo] = *reinterpret_cast<const half8*>(vrow + 32);
        }
        __builtin_amdgcn_sched_barrier(0);   // pin: V loads before stage

        // ---- (2) stage next K tile (stays in flight across this tile) ----
        if (t + 1 < nt) stage_k(t + 1, cur ^ 1);

        // ---- S = Q K^T from LDS (swizzled ds_read_b128) ----
        f32x4 sC[4];
#pragma unroll
        for (int jt = 0; jt < 4; jt++) sC[jt] = (f32x4){0.f, 0.f, 0.f, 0.f};
        const char* kb = (const char*)&Kt[cur][0];
#pragma unroll
        for (int kk = 0; kk < 4; kk++) {
#pragma unroll
            for (int jt = 0; jt < 4; jt++) {
                half8 bk = *(const half8*)(kb + (jt * 16 + lr) * 256 +
                                           ((kk * 64 + lg * 16) ^ ((lr & 7) << 4)));
                sC[jt] = __builtin_amdgcn_mfma_f32_16x16x32_f16(qa[kk], bk, sC[jt], 0, 0, 0);
            }
        }

        // ---- p = exp(s*scale - OFF), row-sum per lane, bounce via LDS ----
        bool diag = (t == nt - 1);
#pragma unroll
        for (int jt = 0; jt < 4; jt++) {
#pragma unroll
            for (int r = 0; r < 4; r++) {
                int row = lg * 4 + r;
                float p = __expf(sC[jt][r] * scale - OFF);
                if (diag && (kv0 + jt * 16 + lr > q0 + row)) p = 0.f;
                lsum[r] += p;
                int colb = (lr + 16 * jt) * 2;
                *(_Float16*)(pbase + row * 128 + (colb ^ ((row & 7) << 4))) = (_Float16)p;
            }
        }

        // ---- O += P V (PV waits only for V loads; stage stays outstanding) ----
#pragma unroll
        for (int kk2 = 0; kk2 < 2; kk2++) {
            half8 pa = *(const half8*)(pbase + lr * 128 +
                                       ((kk2 * 64 + lg * 16) ^ ((lr & 7) << 4)));
#pragma unroll
            for (int jo = 0; jo < 8; jo++) {
                half8 bv = (kk2 == 0) ? vr0[jo] : vr1[jo];
                oacc[jo] = __builtin_amdgcn_mfma_f32_16x16x32_f16(pa, bv, oacc[jo], 0, 0, 0);
            }
        }
        __syncthreads();
    }

    // ---- single end-of-kernel row-sum reduction (16-lane groups) ----
#pragma unroll
    for (int r = 0; r < 4; r++) {
#pragma unroll
        for (int off = 1; off < 16; off <<= 1) lsum[r] += __shfl_xor(lsum[r], off);
    }

    // ---- epilogue: O /= l, store fp16 to [l][h*128+d] ----
#pragma unroll
    for (int jo = 0; jo < 8; jo++) {
#pragma unroll
        for (int r = 0; r < 4; r++) {
            int row = q0 + lg * 4 + r;
            int col = h * HD + jo * 16 + lr;
            out[(size_t)row * D + col] = (_Float16)(oacc[jo][r] / lsum[r]);
        }
    }
}

extern "C" void kernel_launch(void* const* d_in, const int* in_sizes, int n_in,
                              void* d_out, int out_size, void* d_ws, size_t ws_size,
                              hipStream_t stream) {
    const float* x = (const float*)d_in[0];
    const float* wqkv = (const float*)d_in[1];
    const float* wout = (const float*)d_in[2];
    // block_mask (d_in[3]) is tril(ones) == causal; handled analytically.

    _Float16* ws = (_Float16*)d_ws;
    _Float16* xh = ws;                                    // L*D
    _Float16* wqkvh = xh + (size_t)L * D;                 // 3*D*D
    _Float16* wouth = wqkvh + (size_t)3 * D * D;          // D*D
    _Float16* qkh = wouth + (size_t)D * D;                // 2*NH*L*HD
    _Float16* vth = qkh + (size_t)2 * NH * L * HD;        // NH*HD*L
    _Float16* aoh = vth + (size_t)NH * HD * L;            // L*D

    cvt_kernel<<<2048, 256, 0, stream>>>(x, xh, L * D / 4);
    cvt_kernel<<<2048, 256, 0, stream>>>(wqkv, wqkvh, 3 * D * D / 4);
    cvt_kernel<<<2048, 256, 0, stream>>>(wout, wouth, D * D / 4);

    gemm_nt<0><<<dim3(L / 128, 3 * D / 128), 256, 0, stream>>>(
        xh, wqkvh, nullptr, qkh, vth, L, 3 * D, D);

    norm_rope<<<2 * NH * L / 4, 256, 0, stream>>>(qkh);

    attn_kernel<<<512, 256, 0, stream>>>(qkh, vth, aoh);

    gemm_nt<1><<<dim3(L / 128, D / 128), 256, 0, stream>>>(
        aoh, wouth, (float*)d_out, nullptr, nullptr, L, D, D);
}